// Round 1
// baseline (1353.113 us; speedup 1.0000x reference)
//
#include <hip/hip_runtime.h>
#include <hip/hip_bf16.h>

#define N_NODES 50000
#define N_EDGES 800000
#define IN_CH 64
#define EDGE_DIM 8
#define HIDDEN 128
#define NUM_GRAPHS 256

// ---------------------------------------------------------------------------
// Edge kernel: for each edge e, feature j (D = feature dim of current x):
//   msg = relu( x[src[e]][j] + (edge_attr[e] @ We)[j] + be[j] )
//   atomicAdd(agg[dst[e]][j], msg)
// One thread per (edge, feature). D in {64, 128}.
// ---------------------------------------------------------------------------
template<int D>
__global__ __launch_bounds__(256) void edge_kernel(
    const float* __restrict__ h,      // [N, D]
    const int*   __restrict__ src,    // [E]
    const int*   __restrict__ dst,    // [E]
    const float* __restrict__ ea,     // [E, 8]
    const float* __restrict__ We,     // [8, D]
    const float* __restrict__ be,     // [D]
    float*       __restrict__ agg,    // [N, D]
    int E)
{
    int idx = blockIdx.x * blockDim.x + threadIdx.x;
    int e = idx / D;          // D is power of two -> shift
    int j = idx & (D - 1);
    if (e >= E) return;

    int s = src[e];
    int d = dst[e];

    // edge_attr row: 8 floats, 32B-aligned -> two float4 broadcast loads
    const float4* eap = (const float4*)(ea + e * EDGE_DIM);
    float4 ea0 = eap[0];
    float4 ea1 = eap[1];

    float acc = be[j];
    acc += ea0.x * We[0 * D + j];
    acc += ea0.y * We[1 * D + j];
    acc += ea0.z * We[2 * D + j];
    acc += ea0.w * We[3 * D + j];
    acc += ea1.x * We[4 * D + j];
    acc += ea1.y * We[5 * D + j];
    acc += ea1.z * We[6 * D + j];
    acc += ea1.w * We[7 * D + j];

    float msg = h[s * D + j] + acc;
    msg = msg > 0.0f ? msg : 0.0f;
    atomicAdd(&agg[d * D + j], msg);
}

// ---------------------------------------------------------------------------
// Node kernel: out[n][j] = relu( b[j] + sum_k (h[n][k]+agg[n][k]) * W[k][j] )
// 4 nodes per block, 128 threads (one per output feature).
// ---------------------------------------------------------------------------
template<int DIN>
__global__ __launch_bounds__(128) void node_kernel(
    const float* __restrict__ h,     // [N, DIN]
    const float* __restrict__ agg,   // [N, DIN]
    const float* __restrict__ W,     // [DIN, 128]
    const float* __restrict__ b,     // [128]
    float*       __restrict__ out,   // [N, 128]
    int N)
{
    const int TN = 4;
    __shared__ float s[TN][DIN];
    int n0 = blockIdx.x * TN;
    int j = threadIdx.x;

    #pragma unroll
    for (int i = 0; i < TN; ++i) {
        int n = n0 + i;
        for (int k = j; k < DIN; k += 128) {
            s[i][k] = (n < N) ? (h[n * DIN + k] + agg[n * DIN + k]) : 0.0f;
        }
    }
    __syncthreads();

    float bj = b[j];
    float acc[TN];
    #pragma unroll
    for (int i = 0; i < TN; ++i) acc[i] = bj;

    for (int k = 0; k < DIN; k += 4) {
        float w0 = W[(k + 0) * HIDDEN + j];
        float w1 = W[(k + 1) * HIDDEN + j];
        float w2 = W[(k + 2) * HIDDEN + j];
        float w3 = W[(k + 3) * HIDDEN + j];
        #pragma unroll
        for (int i = 0; i < TN; ++i) {
            float4 sv = *(const float4*)&s[i][k];
            acc[i] += sv.x * w0;
            acc[i] += sv.y * w1;
            acc[i] += sv.z * w2;
            acc[i] += sv.w * w3;
        }
    }

    #pragma unroll
    for (int i = 0; i < TN; ++i) {
        int n = n0 + i;
        if (n < N) {
            float v = acc[i];
            out[n * HIDDEN + j] = v > 0.0f ? v : 0.0f;
        }
    }
}

// ---------------------------------------------------------------------------
// Pool: atomic per-(node,feature) sum into per-graph accumulators + counts
// ---------------------------------------------------------------------------
__global__ __launch_bounds__(256) void pool_sum_kernel(
    const float* __restrict__ h,      // [N, 128]
    const int*   __restrict__ batch,  // [N]
    float*       __restrict__ sums,   // [G, 128]
    float*       __restrict__ counts, // [G]
    int N)
{
    int idx = blockIdx.x * blockDim.x + threadIdx.x;
    int n = idx >> 7;
    int j = idx & 127;
    if (n >= N) return;
    int g = batch[n];
    atomicAdd(&sums[g * HIDDEN + j], h[n * HIDDEN + j]);
    if (j == 0) atomicAdd(&counts[g], 1.0f);
}

__global__ __launch_bounds__(256) void pool_div_kernel(
    const float* __restrict__ sums,   // [G, 128]
    const float* __restrict__ counts, // [G]
    float*       __restrict__ out)    // [G, 128]
{
    int idx = blockIdx.x * blockDim.x + threadIdx.x;
    if (idx >= NUM_GRAPHS * HIDDEN) return;
    int g = idx >> 7;
    float c = counts[g];
    out[idx] = sums[idx] / (c > 1.0f ? c : 1.0f);
}

// ---------------------------------------------------------------------------
extern "C" void kernel_launch(void* const* d_in, const int* in_sizes, int n_in,
                              void* d_out, int out_size, void* d_ws, size_t ws_size,
                              hipStream_t stream)
{
    const float* x   = (const float*)d_in[0];      // [N, 64]
    const int*   ei  = (const int*)d_in[1];        // [2, E]
    const float* ea  = (const float*)d_in[2];      // [E, 8]
    const int*   bat = (const int*)d_in[3];        // [N]
    const float* W1  = (const float*)d_in[4];
    const float* b1  = (const float*)d_in[5];
    const float* We1 = (const float*)d_in[6];
    const float* be1 = (const float*)d_in[7];
    const float* W2  = (const float*)d_in[8];
    const float* b2  = (const float*)d_in[9];
    const float* We2 = (const float*)d_in[10];
    const float* be2 = (const float*)d_in[11];
    const float* W3  = (const float*)d_in[12];
    const float* b3  = (const float*)d_in[13];
    const float* We3 = (const float*)d_in[14];
    const float* be3 = (const float*)d_in[15];
    float* out = (float*)d_out;

    const int* src = ei;
    const int* dst = ei + N_EDGES;

    // workspace layout (floats)
    float* agg    = (float*)d_ws;              // [N,128] (only [N,64] used in layer 1)
    float* h1     = agg + (size_t)N_NODES * HIDDEN;
    float* h2     = h1  + (size_t)N_NODES * HIDDEN;
    float* sums   = h2  + (size_t)N_NODES * HIDDEN;   // [G,128]
    float* counts = sums + NUM_GRAPHS * HIDDEN;       // [G]

    const int BLK = 256;

    // ---------------- layer 1 (64 -> 128) ----------------
    hipMemsetAsync(agg, 0, (size_t)N_NODES * IN_CH * sizeof(float), stream);
    {
        long total = (long)N_EDGES * IN_CH;
        int grid = (int)((total + BLK - 1) / BLK);
        edge_kernel<IN_CH><<<grid, BLK, 0, stream>>>(x, src, dst, ea, We1, be1, agg, N_EDGES);
        node_kernel<IN_CH><<<(N_NODES + 3) / 4, 128, 0, stream>>>(x, agg, W1, b1, h1, N_NODES);
    }

    // ---------------- layer 2 (128 -> 128) ----------------
    hipMemsetAsync(agg, 0, (size_t)N_NODES * HIDDEN * sizeof(float), stream);
    {
        long total = (long)N_EDGES * HIDDEN;
        int grid = (int)((total + BLK - 1) / BLK);
        edge_kernel<HIDDEN><<<grid, BLK, 0, stream>>>(h1, src, dst, ea, We2, be2, agg, N_EDGES);
        node_kernel<HIDDEN><<<(N_NODES + 3) / 4, 128, 0, stream>>>(h1, agg, W2, b2, h2, N_NODES);
    }

    // ---------------- layer 3 (128 -> 128) ----------------
    hipMemsetAsync(agg, 0, (size_t)N_NODES * HIDDEN * sizeof(float), stream);
    {
        long total = (long)N_EDGES * HIDDEN;
        int grid = (int)((total + BLK - 1) / BLK);
        edge_kernel<HIDDEN><<<grid, BLK, 0, stream>>>(h2, src, dst, ea, We3, be3, agg, N_EDGES);
        node_kernel<HIDDEN><<<(N_NODES + 3) / 4, 128, 0, stream>>>(h2, agg, W3, b3, h1, N_NODES);
    }

    // ---------------- global mean pool ----------------
    hipMemsetAsync(sums, 0, (NUM_GRAPHS * HIDDEN + NUM_GRAPHS) * sizeof(float), stream);
    {
        long total = (long)N_NODES * HIDDEN;
        int grid = (int)((total + BLK - 1) / BLK);
        pool_sum_kernel<<<grid, BLK, 0, stream>>>(h1, bat, sums, counts, N_NODES);
        pool_div_kernel<<<(NUM_GRAPHS * HIDDEN + BLK - 1) / BLK, BLK, 0, stream>>>(sums, counts, out);
    }
}

// Round 2
// 796.220 us; speedup vs baseline: 1.6994x; 1.6994x over previous
//
#include <hip/hip_runtime.h>
#include <hip/hip_bf16.h>

#define N_NODES 50000
#define N_EDGES 800000
#define IN_CH 64
#define EDGE_DIM 8
#define HIDDEN 128
#define NUM_GRAPHS 256

// ===========================================================================
// CSR build: histogram of dst, exclusive scan, scatter edge ids.
// ===========================================================================
__global__ __launch_bounds__(256) void hist_kernel(
    const int* __restrict__ dst, int* __restrict__ deg, int E)
{
    int i = blockIdx.x * blockDim.x + threadIdx.x;
    if (i < E) atomicAdd(&deg[dst[i]], 1);
}

// blocks of 512 elements (256 threads x 2). Writes inclusive scan into incl,
// per-block totals into blockSums.
__global__ __launch_bounds__(256) void scan1_kernel(
    const int* __restrict__ deg, int* __restrict__ incl,
    int* __restrict__ blockSums, int N)
{
    __shared__ int s[256];
    int b = blockIdx.x, t = threadIdx.x;
    int i0 = b * 512 + 2 * t;
    int a0 = (i0 < N) ? deg[i0] : 0;
    int a1 = (i0 + 1 < N) ? deg[i0 + 1] : 0;
    int ps = a0 + a1;
    s[t] = ps;
    __syncthreads();
    for (int off = 1; off < 256; off <<= 1) {
        int v = (t >= off) ? s[t - off] : 0;
        __syncthreads();
        s[t] += v;
        __syncthreads();
    }
    int exclp = s[t] - ps;
    if (i0 < N)     incl[i0]     = exclp + a0;
    if (i0 + 1 < N) incl[i0 + 1] = exclp + a0 + a1;
    if (t == 255) blockSums[b] = s[255];
}

// single block: exclusive scan of blockSums (B <= 128)
__global__ __launch_bounds__(128) void scan2_kernel(int* __restrict__ blockSums, int B)
{
    __shared__ int s[128];
    int t = threadIdx.x;
    int v = (t < B) ? blockSums[t] : 0;
    s[t] = v;
    __syncthreads();
    for (int off = 1; off < 128; off <<= 1) {
        int u = (t >= off) ? s[t - off] : 0;
        __syncthreads();
        s[t] += u;
        __syncthreads();
    }
    if (t < B) blockSums[t] = s[t] - v;   // exclusive
}

// rowptr[i] = incl[i] - deg[i] + blockOff[i/512]; pos[i] = rowptr[i]
__global__ __launch_bounds__(256) void scan3_kernel(
    const int* __restrict__ incl, const int* __restrict__ deg,
    const int* __restrict__ blockSums, int* __restrict__ rowptr,
    int* __restrict__ pos, int N)
{
    int i = blockIdx.x * blockDim.x + threadIdx.x;
    if (i >= N) return;
    int v = incl[i] - deg[i] + blockSums[i >> 9];
    rowptr[i] = v;
    pos[i] = v;
}

__global__ __launch_bounds__(256) void scatter_kernel(
    const int* __restrict__ dst, int* __restrict__ pos,
    int* __restrict__ eid, int E)
{
    int e = blockIdx.x * blockDim.x + threadIdx.x;
    if (e >= E) return;
    int p = atomicAdd(&pos[dst[e]], 1);
    eid[p] = e;
}

// ===========================================================================
// Node-centric gather-aggregate: one block per node, D threads (feature j).
//   agg[n][j] = sum over incoming edges e: relu( h[src[e]][j] + (ea[e]@We+be)[j] )
// No fp32 atomics. Edge ids / src / ea prefetched into LDS per chunk.
// ===========================================================================
template<int D>
__global__ __launch_bounds__(128) void gather_agg_kernel(
    const float* __restrict__ h,       // [N, D]
    const int*   __restrict__ src,     // [E]
    const float* __restrict__ ea,      // [E, 8]
    const int*   __restrict__ eid,     // [E] CSR edge list
    const int*   __restrict__ rowptr,  // [N]
    const int*   __restrict__ deg,     // [N]
    const float* __restrict__ We,      // [8, D]
    const float* __restrict__ be,      // [D]
    float*       __restrict__ agg,     // [N, D]
    int N)
{
    __shared__ int   s_src[128];
    __shared__ float s_ea[128][8];

    int n = blockIdx.x;
    int j = threadIdx.x;   // 0..D-1

    float w[8];
    #pragma unroll
    for (int k = 0; k < 8; ++k) w[k] = We[k * D + j];
    float bej = be[j];

    int start = rowptr[n];
    int dg = deg[n];

    float acc = 0.0f;
    for (int base = 0; base < dg; base += D) {
        int cnt = dg - base;
        if (cnt > D) cnt = D;
        if (j < cnt) {
            int e = eid[start + base + j];
            s_src[j] = src[e];
            const float4* eap = (const float4*)(ea + (size_t)e * EDGE_DIM);
            float4 a0 = eap[0];
            float4 a1 = eap[1];
            *(float4*)&s_ea[j][0] = a0;
            *(float4*)&s_ea[j][4] = a1;
        }
        __syncthreads();
        for (int p = 0; p < cnt; ++p) {
            int s = s_src[p];
            float m = h[(size_t)s * D + j] + bej
                    + s_ea[p][0] * w[0] + s_ea[p][1] * w[1]
                    + s_ea[p][2] * w[2] + s_ea[p][3] * w[3]
                    + s_ea[p][4] * w[4] + s_ea[p][5] * w[5]
                    + s_ea[p][6] * w[6] + s_ea[p][7] * w[7];
            acc += (m > 0.0f) ? m : 0.0f;
        }
        __syncthreads();
    }
    agg[(size_t)n * D + j] = acc;
}

// ===========================================================================
// Node GEMM: out[n][j] = relu( b[j] + sum_k (h[n][k]+agg[n][k]) * W[k][j] )
// ===========================================================================
template<int DIN>
__global__ __launch_bounds__(128) void node_kernel(
    const float* __restrict__ h,     // [N, DIN]
    const float* __restrict__ agg,   // [N, DIN]
    const float* __restrict__ W,     // [DIN, 128]
    const float* __restrict__ b,     // [128]
    float*       __restrict__ out,   // [N, 128]
    int N)
{
    const int TN = 4;
    __shared__ float s[TN][DIN];
    int n0 = blockIdx.x * TN;
    int j = threadIdx.x;

    #pragma unroll
    for (int i = 0; i < TN; ++i) {
        int n = n0 + i;
        for (int k = j; k < DIN; k += 128) {
            s[i][k] = (n < N) ? (h[n * DIN + k] + agg[n * DIN + k]) : 0.0f;
        }
    }
    __syncthreads();

    float bj = b[j];
    float acc[TN];
    #pragma unroll
    for (int i = 0; i < TN; ++i) acc[i] = bj;

    for (int k = 0; k < DIN; k += 4) {
        float w0 = W[(k + 0) * HIDDEN + j];
        float w1 = W[(k + 1) * HIDDEN + j];
        float w2 = W[(k + 2) * HIDDEN + j];
        float w3 = W[(k + 3) * HIDDEN + j];
        #pragma unroll
        for (int i = 0; i < TN; ++i) {
            float4 sv = *(const float4*)&s[i][k];
            acc[i] += sv.x * w0;
            acc[i] += sv.y * w1;
            acc[i] += sv.z * w2;
            acc[i] += sv.w * w3;
        }
    }

    #pragma unroll
    for (int i = 0; i < TN; ++i) {
        int n = n0 + i;
        if (n < N) {
            float v = acc[i];
            out[n * HIDDEN + j] = v > 0.0f ? v : 0.0f;
        }
    }
}

// ===========================================================================
// Pool
// ===========================================================================
__global__ __launch_bounds__(256) void pool_sum_kernel(
    const float* __restrict__ h,      // [N, 128]
    const int*   __restrict__ batch,  // [N]
    float*       __restrict__ sums,   // [G, 128]
    float*       __restrict__ counts, // [G]
    int N)
{
    int idx = blockIdx.x * blockDim.x + threadIdx.x;
    int n = idx >> 7;
    int j = idx & 127;
    if (n >= N) return;
    int g = batch[n];
    atomicAdd(&sums[g * HIDDEN + j], h[n * HIDDEN + j]);
    if (j == 0) atomicAdd(&counts[g], 1.0f);
}

__global__ __launch_bounds__(256) void pool_div_kernel(
    const float* __restrict__ sums,   // [G, 128]
    const float* __restrict__ counts, // [G]
    float*       __restrict__ out)    // [G, 128]
{
    int idx = blockIdx.x * blockDim.x + threadIdx.x;
    if (idx >= NUM_GRAPHS * HIDDEN) return;
    int g = idx >> 7;
    float c = counts[g];
    out[idx] = sums[idx] / (c > 1.0f ? c : 1.0f);
}

// ===========================================================================
extern "C" void kernel_launch(void* const* d_in, const int* in_sizes, int n_in,
                              void* d_out, int out_size, void* d_ws, size_t ws_size,
                              hipStream_t stream)
{
    const float* x   = (const float*)d_in[0];      // [N, 64]
    const int*   ei  = (const int*)d_in[1];        // [2, E]
    const float* ea  = (const float*)d_in[2];      // [E, 8]
    const int*   bat = (const int*)d_in[3];        // [N]
    const float* W1  = (const float*)d_in[4];
    const float* b1  = (const float*)d_in[5];
    const float* We1 = (const float*)d_in[6];
    const float* be1 = (const float*)d_in[7];
    const float* W2  = (const float*)d_in[8];
    const float* b2  = (const float*)d_in[9];
    const float* We2 = (const float*)d_in[10];
    const float* be2 = (const float*)d_in[11];
    const float* W3  = (const float*)d_in[12];
    const float* b3  = (const float*)d_in[13];
    const float* We3 = (const float*)d_in[14];
    const float* be3 = (const float*)d_in[15];
    float* out = (float*)d_out;

    const int* src = ei;
    const int* dst = ei + N_EDGES;

    // ---------------- workspace layout ----------------
    int* deg       = (int*)d_ws;                 // [N]
    int* rowptr    = deg + N_NODES;              // [N]
    int* pos       = rowptr + N_NODES;           // [N] (also incl-scan temp)
    int* eid       = pos + N_NODES;              // [E]
    int* blockSums = eid + N_EDGES;              // [128]
    float* agg     = (float*)(blockSums + 128);              // [N,128]
    float* h1      = agg + (size_t)N_NODES * HIDDEN;         // [N,128]
    float* h2      = h1  + (size_t)N_NODES * HIDDEN;         // [N,128]
    float* sums    = h2  + (size_t)N_NODES * HIDDEN;         // [G,128]
    float* counts  = sums + NUM_GRAPHS * HIDDEN;             // [G]

    const int BLK = 256;
    const int NB_E = (N_EDGES + BLK - 1) / BLK;
    const int NB_N = (N_NODES + BLK - 1) / BLK;
    const int SCAN_B = (N_NODES + 511) / 512;    // 98

    // ---------------- CSR build (once; shared by all 3 layers) ----------------
    hipMemsetAsync(deg, 0, N_NODES * sizeof(int), stream);
    hist_kernel<<<NB_E, BLK, 0, stream>>>(dst, deg, N_EDGES);
    scan1_kernel<<<SCAN_B, 256, 0, stream>>>(deg, pos, blockSums, N_NODES);
    scan2_kernel<<<1, 128, 0, stream>>>(blockSums, SCAN_B);
    scan3_kernel<<<NB_N, BLK, 0, stream>>>(pos, deg, blockSums, rowptr, pos, N_NODES);
    scatter_kernel<<<NB_E, BLK, 0, stream>>>(dst, pos, eid, N_EDGES);

    // ---------------- layer 1 (64 -> 128) ----------------
    gather_agg_kernel<IN_CH><<<N_NODES, IN_CH, 0, stream>>>(
        x, src, ea, eid, rowptr, deg, We1, be1, agg, N_NODES);
    node_kernel<IN_CH><<<(N_NODES + 3) / 4, 128, 0, stream>>>(x, agg, W1, b1, h1, N_NODES);

    // ---------------- layer 2 (128 -> 128) ----------------
    gather_agg_kernel<HIDDEN><<<N_NODES, HIDDEN, 0, stream>>>(
        h1, src, ea, eid, rowptr, deg, We2, be2, agg, N_NODES);
    node_kernel<HIDDEN><<<(N_NODES + 3) / 4, 128, 0, stream>>>(h1, agg, W2, b2, h2, N_NODES);

    // ---------------- layer 3 (128 -> 128) ----------------
    gather_agg_kernel<HIDDEN><<<N_NODES, HIDDEN, 0, stream>>>(
        h2, src, ea, eid, rowptr, deg, We3, be3, agg, N_NODES);
    node_kernel<HIDDEN><<<(N_NODES + 3) / 4, 128, 0, stream>>>(h2, agg, W3, b3, h1, N_NODES);

    // ---------------- global mean pool ----------------
    hipMemsetAsync(sums, 0, (NUM_GRAPHS * HIDDEN + NUM_GRAPHS) * sizeof(float), stream);
    {
        long total = (long)N_NODES * HIDDEN;
        int grid = (int)((total + BLK - 1) / BLK);
        pool_sum_kernel<<<grid, BLK, 0, stream>>>(h1, bat, sums, counts, N_NODES);
        pool_div_kernel<<<(NUM_GRAPHS * HIDDEN + BLK - 1) / BLK, BLK, 0, stream>>>(sums, counts, out);
    }
}

// Round 3
// 633.435 us; speedup vs baseline: 2.1362x; 1.2570x over previous
//
#include <hip/hip_runtime.h>
#include <hip/hip_bf16.h>

#define N_NODES 50000
#define N_EDGES 800000
#define IN_CH 64
#define EDGE_DIM 8
#define HIDDEN 128
#define NUM_GRAPHS 256

// ===========================================================================
// CSR build: histogram of dst, exclusive scan, scatter edge ids.
// ===========================================================================
__global__ __launch_bounds__(256) void hist_kernel(
    const int* __restrict__ dst, int* __restrict__ deg, int E)
{
    int i = blockIdx.x * blockDim.x + threadIdx.x;
    if (i < E) atomicAdd(&deg[dst[i]], 1);
}

// blocks of 512 elements (256 threads x 2). Writes inclusive scan into incl,
// per-block totals into blockSums.
__global__ __launch_bounds__(256) void scan1_kernel(
    const int* __restrict__ deg, int* __restrict__ incl,
    int* __restrict__ blockSums, int N)
{
    __shared__ int s[256];
    int b = blockIdx.x, t = threadIdx.x;
    int i0 = b * 512 + 2 * t;
    int a0 = (i0 < N) ? deg[i0] : 0;
    int a1 = (i0 + 1 < N) ? deg[i0 + 1] : 0;
    int ps = a0 + a1;
    s[t] = ps;
    __syncthreads();
    for (int off = 1; off < 256; off <<= 1) {
        int v = (t >= off) ? s[t - off] : 0;
        __syncthreads();
        s[t] += v;
        __syncthreads();
    }
    int exclp = s[t] - ps;
    if (i0 < N)     incl[i0]     = exclp + a0;
    if (i0 + 1 < N) incl[i0 + 1] = exclp + a0 + a1;
    if (t == 255) blockSums[b] = s[255];
}

// single block: exclusive scan of blockSums (B <= 128)
__global__ __launch_bounds__(128) void scan2_kernel(int* __restrict__ blockSums, int B)
{
    __shared__ int s[128];
    int t = threadIdx.x;
    int v = (t < B) ? blockSums[t] : 0;
    s[t] = v;
    __syncthreads();
    for (int off = 1; off < 128; off <<= 1) {
        int u = (t >= off) ? s[t - off] : 0;
        __syncthreads();
        s[t] += u;
        __syncthreads();
    }
    if (t < B) blockSums[t] = s[t] - v;   // exclusive
}

// rowptr[i] = incl[i] - deg[i] + blockOff[i/512]; pos[i] = rowptr[i]
__global__ __launch_bounds__(256) void scan3_kernel(
    const int* __restrict__ incl, const int* __restrict__ deg,
    const int* __restrict__ blockSums, int* __restrict__ rowptr,
    int* __restrict__ pos, int N)
{
    int i = blockIdx.x * blockDim.x + threadIdx.x;
    if (i >= N) return;
    int v = incl[i] - deg[i] + blockSums[i >> 9];
    rowptr[i] = v;
    pos[i] = v;
}

__global__ __launch_bounds__(256) void scatter_kernel(
    const int* __restrict__ dst, int* __restrict__ pos,
    int* __restrict__ eid, int E)
{
    int e = blockIdx.x * blockDim.x + threadIdx.x;
    if (e >= E) return;
    int p = atomicAdd(&pos[dst[e]], 1);
    eid[p] = e;
}

// ===========================================================================
// Node-centric gather-aggregate: one block per node, D threads (feature j).
//   agg[n][j] = sum over incoming edges e: relu( h[src[e]][j] + (ea[e]@We+be)[j] )
// No fp32 atomics. Edge ids / src / ea prefetched into LDS per chunk.
// ===========================================================================
template<int D>
__global__ __launch_bounds__(128) void gather_agg_kernel(
    const float* __restrict__ h,       // [N, D]
    const int*   __restrict__ src,     // [E]
    const float* __restrict__ ea,      // [E, 8]
    const int*   __restrict__ eid,     // [E] CSR edge list
    const int*   __restrict__ rowptr,  // [N]
    const int*   __restrict__ deg,     // [N]
    const float* __restrict__ We,      // [8, D]
    const float* __restrict__ be,      // [D]
    float*       __restrict__ agg,     // [N, D]
    int N)
{
    __shared__ int   s_src[128];
    __shared__ float s_ea[128][8];

    int n = blockIdx.x;
    int j = threadIdx.x;   // 0..D-1

    float w[8];
    #pragma unroll
    for (int k = 0; k < 8; ++k) w[k] = We[k * D + j];
    float bej = be[j];

    int start = rowptr[n];
    int dg = deg[n];

    float acc = 0.0f;
    for (int base = 0; base < dg; base += D) {
        int cnt = dg - base;
        if (cnt > D) cnt = D;
        if (j < cnt) {
            int e = eid[start + base + j];
            s_src[j] = src[e];
            const float4* eap = (const float4*)(ea + (size_t)e * EDGE_DIM);
            float4 a0 = eap[0];
            float4 a1 = eap[1];
            *(float4*)&s_ea[j][0] = a0;
            *(float4*)&s_ea[j][4] = a1;
        }
        __syncthreads();
        for (int p = 0; p < cnt; ++p) {
            int s = s_src[p];
            float m = h[(size_t)s * D + j] + bej
                    + s_ea[p][0] * w[0] + s_ea[p][1] * w[1]
                    + s_ea[p][2] * w[2] + s_ea[p][3] * w[3]
                    + s_ea[p][4] * w[4] + s_ea[p][5] * w[5]
                    + s_ea[p][6] * w[6] + s_ea[p][7] * w[7];
            acc += (m > 0.0f) ? m : 0.0f;
        }
        __syncthreads();
    }
    agg[(size_t)n * D + j] = acc;
}

// ===========================================================================
// Node GEMM: out[n][j] = relu( b[j] + sum_k (h[n][k]+agg[n][k]) * W[k][j] )
// 8 nodes per block, 128 threads (one per output feature).
// ===========================================================================
template<int DIN>
__global__ __launch_bounds__(128) void node_kernel(
    const float* __restrict__ h,     // [N, DIN]
    const float* __restrict__ agg,   // [N, DIN]
    const float* __restrict__ W,     // [DIN, 128]
    const float* __restrict__ b,     // [128]
    float*       __restrict__ out,   // [N, 128]
    int N)
{
    const int TN = 8;
    __shared__ float s[TN][DIN];
    int n0 = blockIdx.x * TN;
    int j = threadIdx.x;

    #pragma unroll
    for (int i = 0; i < TN; ++i) {
        int n = n0 + i;
        for (int k = j; k < DIN; k += 128) {
            s[i][k] = (n < N) ? (h[n * DIN + k] + agg[n * DIN + k]) : 0.0f;
        }
    }
    __syncthreads();

    float bj = b[j];
    float acc[TN];
    #pragma unroll
    for (int i = 0; i < TN; ++i) acc[i] = bj;

    for (int k = 0; k < DIN; k += 4) {
        float w0 = W[(k + 0) * HIDDEN + j];
        float w1 = W[(k + 1) * HIDDEN + j];
        float w2 = W[(k + 2) * HIDDEN + j];
        float w3 = W[(k + 3) * HIDDEN + j];
        #pragma unroll
        for (int i = 0; i < TN; ++i) {
            float4 sv = *(const float4*)&s[i][k];
            acc[i] += sv.x * w0;
            acc[i] += sv.y * w1;
            acc[i] += sv.z * w2;
            acc[i] += sv.w * w3;
        }
    }

    #pragma unroll
    for (int i = 0; i < TN; ++i) {
        int n = n0 + i;
        if (n < N) {
            float v = acc[i];
            out[n * HIDDEN + j] = v > 0.0f ? v : 0.0f;
        }
    }
}

// ===========================================================================
// Pool: batch is SORTED -> one block per graph, binary-search the node range,
// direct coalesced sum, no atomics. Fuses the divide.
// ===========================================================================
__global__ __launch_bounds__(128) void pool_kernel(
    const float* __restrict__ h,      // [N, 128]
    const int*   __restrict__ batch,  // [N] sorted
    float*       __restrict__ out,    // [G, 128]
    int N)
{
    __shared__ int s_lo, s_hi;
    int g = blockIdx.x;
    int j = threadIdx.x;

    if (j == 0) {
        int lo = 0, hi = N;
        while (lo < hi) { int m = (lo + hi) >> 1; if (batch[m] < g) lo = m + 1; else hi = m; }
        s_lo = lo;
        int lo2 = lo, hi2 = N;
        while (lo2 < hi2) { int m = (lo2 + hi2) >> 1; if (batch[m] < g + 1) lo2 = m + 1; else hi2 = m; }
        s_hi = lo2;
    }
    __syncthreads();

    int lo = s_lo, hi = s_hi;
    float acc = 0.0f;
    #pragma unroll 4
    for (int n = lo; n < hi; ++n) {
        acc += h[(size_t)n * HIDDEN + j];
    }
    float c = (float)(hi - lo);
    out[g * HIDDEN + j] = acc / (c > 1.0f ? c : 1.0f);
}

// ===========================================================================
extern "C" void kernel_launch(void* const* d_in, const int* in_sizes, int n_in,
                              void* d_out, int out_size, void* d_ws, size_t ws_size,
                              hipStream_t stream)
{
    const float* x   = (const float*)d_in[0];      // [N, 64]
    const int*   ei  = (const int*)d_in[1];        // [2, E]
    const float* ea  = (const float*)d_in[2];      // [E, 8]
    const int*   bat = (const int*)d_in[3];        // [N]
    const float* W1  = (const float*)d_in[4];
    const float* b1  = (const float*)d_in[5];
    const float* We1 = (const float*)d_in[6];
    const float* be1 = (const float*)d_in[7];
    const float* W2  = (const float*)d_in[8];
    const float* b2  = (const float*)d_in[9];
    const float* We2 = (const float*)d_in[10];
    const float* be2 = (const float*)d_in[11];
    const float* W3  = (const float*)d_in[12];
    const float* b3  = (const float*)d_in[13];
    const float* We3 = (const float*)d_in[14];
    const float* be3 = (const float*)d_in[15];
    float* out = (float*)d_out;

    const int* src = ei;
    const int* dst = ei + N_EDGES;

    // ---------------- workspace layout ----------------
    int* deg       = (int*)d_ws;                 // [N]
    int* rowptr    = deg + N_NODES;              // [N]
    int* pos       = rowptr + N_NODES;           // [N] (also incl-scan temp)
    int* eid       = pos + N_NODES;              // [E]
    int* blockSums = eid + N_EDGES;              // [128]
    float* agg     = (float*)(blockSums + 128);              // [N,128]
    float* h1      = agg + (size_t)N_NODES * HIDDEN;         // [N,128]
    float* h2      = h1  + (size_t)N_NODES * HIDDEN;         // [N,128]

    const int BLK = 256;
    const int NB_E = (N_EDGES + BLK - 1) / BLK;
    const int NB_N = (N_NODES + BLK - 1) / BLK;
    const int SCAN_B = (N_NODES + 511) / 512;    // 98

    // ---------------- CSR build (once; shared by all 3 layers) ----------------
    hipMemsetAsync(deg, 0, N_NODES * sizeof(int), stream);
    hist_kernel<<<NB_E, BLK, 0, stream>>>(dst, deg, N_EDGES);
    scan1_kernel<<<SCAN_B, 256, 0, stream>>>(deg, pos, blockSums, N_NODES);
    scan2_kernel<<<1, 128, 0, stream>>>(blockSums, SCAN_B);
    scan3_kernel<<<NB_N, BLK, 0, stream>>>(pos, deg, blockSums, rowptr, pos, N_NODES);
    scatter_kernel<<<NB_E, BLK, 0, stream>>>(dst, pos, eid, N_EDGES);

    // ---------------- layer 1 (64 -> 128) ----------------
    gather_agg_kernel<IN_CH><<<N_NODES, IN_CH, 0, stream>>>(
        x, src, ea, eid, rowptr, deg, We1, be1, agg, N_NODES);
    node_kernel<IN_CH><<<(N_NODES + 7) / 8, 128, 0, stream>>>(x, agg, W1, b1, h1, N_NODES);

    // ---------------- layer 2 (128 -> 128) ----------------
    gather_agg_kernel<HIDDEN><<<N_NODES, HIDDEN, 0, stream>>>(
        h1, src, ea, eid, rowptr, deg, We2, be2, agg, N_NODES);
    node_kernel<HIDDEN><<<(N_NODES + 7) / 8, 128, 0, stream>>>(h1, agg, W2, b2, h2, N_NODES);

    // ---------------- layer 3 (128 -> 128) ----------------
    gather_agg_kernel<HIDDEN><<<N_NODES, HIDDEN, 0, stream>>>(
        h2, src, ea, eid, rowptr, deg, We3, be3, agg, N_NODES);
    node_kernel<HIDDEN><<<(N_NODES + 7) / 8, 128, 0, stream>>>(h2, agg, W3, b3, h1, N_NODES);

    // ---------------- global mean pool (segmented, no atomics) ----------------
    pool_kernel<<<NUM_GRAPHS, 128, 0, stream>>>(h1, bat, out, N_NODES);
}

// Round 4
// 610.529 us; speedup vs baseline: 2.2163x; 1.0375x over previous
//
#include <hip/hip_runtime.h>
#include <hip/hip_bf16.h>

#define N_NODES 50000
#define N_EDGES 800000
#define IN_CH 64
#define EDGE_DIM 8
#define HIDDEN 128
#define NUM_GRAPHS 256

// ===========================================================================
// CSR build: histogram of dst, exclusive scan, scatter edge ids.
// ===========================================================================
__global__ __launch_bounds__(256) void hist_kernel(
    const int* __restrict__ dst, int* __restrict__ deg, int E)
{
    int i = blockIdx.x * blockDim.x + threadIdx.x;
    if (i < E) atomicAdd(&deg[dst[i]], 1);
}

__global__ __launch_bounds__(256) void scan1_kernel(
    const int* __restrict__ deg, int* __restrict__ incl,
    int* __restrict__ blockSums, int N)
{
    __shared__ int s[256];
    int b = blockIdx.x, t = threadIdx.x;
    int i0 = b * 512 + 2 * t;
    int a0 = (i0 < N) ? deg[i0] : 0;
    int a1 = (i0 + 1 < N) ? deg[i0 + 1] : 0;
    int ps = a0 + a1;
    s[t] = ps;
    __syncthreads();
    for (int off = 1; off < 256; off <<= 1) {
        int v = (t >= off) ? s[t - off] : 0;
        __syncthreads();
        s[t] += v;
        __syncthreads();
    }
    int exclp = s[t] - ps;
    if (i0 < N)     incl[i0]     = exclp + a0;
    if (i0 + 1 < N) incl[i0 + 1] = exclp + a0 + a1;
    if (t == 255) blockSums[b] = s[255];
}

__global__ __launch_bounds__(128) void scan2_kernel(int* __restrict__ blockSums, int B)
{
    __shared__ int s[128];
    int t = threadIdx.x;
    int v = (t < B) ? blockSums[t] : 0;
    s[t] = v;
    __syncthreads();
    for (int off = 1; off < 128; off <<= 1) {
        int u = (t >= off) ? s[t - off] : 0;
        __syncthreads();
        s[t] += u;
        __syncthreads();
    }
    if (t < B) blockSums[t] = s[t] - v;   // exclusive
}

__global__ __launch_bounds__(256) void scan3_kernel(
    const int* __restrict__ incl, const int* __restrict__ deg,
    const int* __restrict__ blockSums, int* __restrict__ rowptr,
    int* __restrict__ pos, int N)
{
    int i = blockIdx.x * blockDim.x + threadIdx.x;
    if (i >= N) return;
    int v = incl[i] - deg[i] + blockSums[i >> 9];
    rowptr[i] = v;
    pos[i] = v;
}

__global__ __launch_bounds__(256) void scatter_kernel(
    const int* __restrict__ dst, int* __restrict__ pos,
    int* __restrict__ eid, int E)
{
    int e = blockIdx.x * blockDim.x + threadIdx.x;
    if (e >= E) return;
    int p = atomicAdd(&pos[dst[e]], 1);
    eid[p] = e;
}

// ===========================================================================
// Node-centric gather-aggregate, fused with the self term:
//   xs[n][j] = h[n][j] + sum over incoming e: relu( h[src[e]][j] + (ea@We+be)[j] )
// One block per node, D threads. No fp32 atomics.
// ===========================================================================
template<int D>
__global__ __launch_bounds__(128) void gather_xs_kernel(
    const float* __restrict__ h,       // [N, D]
    const int*   __restrict__ src,     // [E]
    const float* __restrict__ ea,      // [E, 8]
    const int*   __restrict__ eid,     // [E] CSR edge list
    const int*   __restrict__ rowptr,  // [N]
    const int*   __restrict__ deg,     // [N]
    const float* __restrict__ We,      // [8, D]
    const float* __restrict__ be,      // [D]
    float*       __restrict__ xs,      // [N, D]  output: h + agg
    int N)
{
    __shared__ int   s_src[128];
    __shared__ float s_ea[128][8];

    int n = blockIdx.x;
    int j = threadIdx.x;   // 0..D-1

    float w[8];
    #pragma unroll
    for (int k = 0; k < 8; ++k) w[k] = We[k * D + j];
    float bej = be[j];

    int start = rowptr[n];
    int dg = deg[n];

    float acc = h[(size_t)n * D + j];   // self term (eps = 0)
    for (int base = 0; base < dg; base += D) {
        int cnt = dg - base;
        if (cnt > D) cnt = D;
        if (j < cnt) {
            int e = eid[start + base + j];
            s_src[j] = src[e];
            const float4* eap = (const float4*)(ea + (size_t)e * EDGE_DIM);
            float4 a0 = eap[0];
            float4 a1 = eap[1];
            *(float4*)&s_ea[j][0] = a0;
            *(float4*)&s_ea[j][4] = a1;
        }
        __syncthreads();
        for (int p = 0; p < cnt; ++p) {
            int s = s_src[p];
            float m = h[(size_t)s * D + j] + bej
                    + s_ea[p][0] * w[0] + s_ea[p][1] * w[1]
                    + s_ea[p][2] * w[2] + s_ea[p][3] * w[3]
                    + s_ea[p][4] * w[4] + s_ea[p][5] * w[5]
                    + s_ea[p][6] * w[6] + s_ea[p][7] * w[7];
            acc += (m > 0.0f) ? m : 0.0f;
        }
        __syncthreads();
    }
    xs[(size_t)n * D + j] = acc;
}

// ===========================================================================
// Node GEMM: out[n][j] = relu( b[j] + sum_k xs[n][k] * W[k][j] )
// 256 threads, 16 nodes/block (N divisible by 16). j = tid&127 is the output
// feature; tid>>7 selects which 8-node group this wave-pair handles.
// xs rows are wave-uniform -> forced scalar loads via readfirstlane, so the
// inner loop is v_fma with one SGPR operand; W columns are coalesced vector
// loads. Low VGPR count -> high occupancy.
// ===========================================================================
template<int DIN>
__global__ __launch_bounds__(256, 4) void node_kernel(
    const float* __restrict__ xs,    // [N, DIN]
    const float* __restrict__ W,     // [DIN, 128]
    const float* __restrict__ b,     // [128]
    float*       __restrict__ out,   // [N, 128]
    int N)
{
    const int NPH = 8;                      // nodes per half
    int j    = threadIdx.x & 127;
    int half = threadIdx.x >> 7;
    int n0   = blockIdx.x * 16 + half * NPH;

    float bj = b[j];
    float acc[NPH];
    #pragma unroll
    for (int i = 0; i < NPH; ++i) acc[i] = bj;

    // wave-uniform row base offsets (readfirstlane -> SGPR -> s_load path)
    const float* row[NPH];
    #pragma unroll
    for (int i = 0; i < NPH; ++i) {
        int off = __builtin_amdgcn_readfirstlane((n0 + i) * DIN);
        row[i] = xs + off;
    }

    for (int k = 0; k < DIN; k += 4) {
        float w0 = W[(k + 0) * HIDDEN + j];
        float w1 = W[(k + 1) * HIDDEN + j];
        float w2 = W[(k + 2) * HIDDEN + j];
        float w3 = W[(k + 3) * HIDDEN + j];
        #pragma unroll
        for (int i = 0; i < NPH; ++i) {
            float4 xv = *(const float4*)(row[i] + k);
            acc[i] = fmaf(xv.x, w0, acc[i]);
            acc[i] = fmaf(xv.y, w1, acc[i]);
            acc[i] = fmaf(xv.z, w2, acc[i]);
            acc[i] = fmaf(xv.w, w3, acc[i]);
        }
    }

    #pragma unroll
    for (int i = 0; i < NPH; ++i) {
        int n = n0 + i;
        float v = acc[i];
        out[(size_t)n * HIDDEN + j] = v > 0.0f ? v : 0.0f;
    }
}

// ===========================================================================
// Pool: batch is SORTED -> one block per graph, binary-search the node range,
// direct coalesced sum, no atomics. Fuses the divide.
// ===========================================================================
__global__ __launch_bounds__(128) void pool_kernel(
    const float* __restrict__ h,      // [N, 128]
    const int*   __restrict__ batch,  // [N] sorted
    float*       __restrict__ out,    // [G, 128]
    int N)
{
    __shared__ int s_lo, s_hi;
    int g = blockIdx.x;
    int j = threadIdx.x;

    if (j == 0) {
        int lo = 0, hi = N;
        while (lo < hi) { int m = (lo + hi) >> 1; if (batch[m] < g) lo = m + 1; else hi = m; }
        s_lo = lo;
        int lo2 = lo, hi2 = N;
        while (lo2 < hi2) { int m = (lo2 + hi2) >> 1; if (batch[m] < g + 1) lo2 = m + 1; else hi2 = m; }
        s_hi = lo2;
    }
    __syncthreads();

    int lo = s_lo, hi = s_hi;
    float acc = 0.0f;
    #pragma unroll 4
    for (int n = lo; n < hi; ++n) {
        acc += h[(size_t)n * HIDDEN + j];
    }
    float c = (float)(hi - lo);
    out[g * HIDDEN + j] = acc / (c > 1.0f ? c : 1.0f);
}

// ===========================================================================
extern "C" void kernel_launch(void* const* d_in, const int* in_sizes, int n_in,
                              void* d_out, int out_size, void* d_ws, size_t ws_size,
                              hipStream_t stream)
{
    const float* x   = (const float*)d_in[0];      // [N, 64]
    const int*   ei  = (const int*)d_in[1];        // [2, E]
    const float* ea  = (const float*)d_in[2];      // [E, 8]
    const int*   bat = (const int*)d_in[3];        // [N]
    const float* W1  = (const float*)d_in[4];
    const float* b1  = (const float*)d_in[5];
    const float* We1 = (const float*)d_in[6];
    const float* be1 = (const float*)d_in[7];
    const float* W2  = (const float*)d_in[8];
    const float* b2  = (const float*)d_in[9];
    const float* We2 = (const float*)d_in[10];
    const float* be2 = (const float*)d_in[11];
    const float* W3  = (const float*)d_in[12];
    const float* b3  = (const float*)d_in[13];
    const float* We3 = (const float*)d_in[14];
    const float* be3 = (const float*)d_in[15];
    float* out = (float*)d_out;

    const int* src = ei;
    const int* dst = ei + N_EDGES;

    // ---------------- workspace layout ----------------
    int* deg       = (int*)d_ws;                 // [N]
    int* rowptr    = deg + N_NODES;              // [N]
    int* pos       = rowptr + N_NODES;           // [N] (also incl-scan temp)
    int* eid       = pos + N_NODES;              // [E]
    int* blockSums = eid + N_EDGES;              // [128]
    float* xs      = (float*)(blockSums + 128);              // [N,128]
    float* h1      = xs + (size_t)N_NODES * HIDDEN;          // [N,128]
    float* h2      = h1 + (size_t)N_NODES * HIDDEN;          // [N,128]

    const int BLK = 256;
    const int NB_E = (N_EDGES + BLK - 1) / BLK;
    const int NB_N = (N_NODES + BLK - 1) / BLK;
    const int SCAN_B = (N_NODES + 511) / 512;    // 98

    // ---------------- CSR build (once; shared by all 3 layers) ----------------
    hipMemsetAsync(deg, 0, N_NODES * sizeof(int), stream);
    hist_kernel<<<NB_E, BLK, 0, stream>>>(dst, deg, N_EDGES);
    scan1_kernel<<<SCAN_B, 256, 0, stream>>>(deg, pos, blockSums, N_NODES);
    scan2_kernel<<<1, 128, 0, stream>>>(blockSums, SCAN_B);
    scan3_kernel<<<NB_N, BLK, 0, stream>>>(pos, deg, blockSums, rowptr, pos, N_NODES);
    scatter_kernel<<<NB_E, BLK, 0, stream>>>(dst, pos, eid, N_EDGES);

    // ---------------- layer 1 (64 -> 128) ----------------
    gather_xs_kernel<IN_CH><<<N_NODES, IN_CH, 0, stream>>>(
        x, src, ea, eid, rowptr, deg, We1, be1, xs, N_NODES);
    node_kernel<IN_CH><<<N_NODES / 16, 256, 0, stream>>>(xs, W1, b1, h1, N_NODES);

    // ---------------- layer 2 (128 -> 128) ----------------
    gather_xs_kernel<HIDDEN><<<N_NODES, HIDDEN, 0, stream>>>(
        h1, src, ea, eid, rowptr, deg, We2, be2, xs, N_NODES);
    node_kernel<HIDDEN><<<N_NODES / 16, 256, 0, stream>>>(xs, W2, b2, h2, N_NODES);

    // ---------------- layer 3 (128 -> 128) ----------------
    gather_xs_kernel<HIDDEN><<<N_NODES, HIDDEN, 0, stream>>>(
        h2, src, ea, eid, rowptr, deg, We3, be3, xs, N_NODES);
    node_kernel<HIDDEN><<<N_NODES / 16, 256, 0, stream>>>(xs, W3, b3, h1, N_NODES);

    // ---------------- global mean pool (segmented, no atomics) ----------------
    pool_kernel<<<NUM_GRAPHS, 128, 0, stream>>>(h1, bat, out, N_NODES);
}